// Round 1
// baseline (541.727 us; speedup 1.0000x reference)
//
#include <hip/hip_runtime.h>
#include <hip/hip_bf16.h>
#include <cstdint>
#include <cstddef>

#define S_ 256
#define N_ 1024
#define H_ 512
#define AD_ 128
static constexpr int M_TOTAL = N_ * S_;   // 262144 rows per stream

typedef __attribute__((ext_vector_type(8))) short short8;
typedef __attribute__((ext_vector_type(4))) float f32x4;

__device__ __forceinline__ unsigned short f2bf(float f) {
  unsigned int u = __float_as_uint(f);
  unsigned int r = (u + 0x7FFFu + ((u >> 16) & 1u)) >> 16;  // RNE
  return (unsigned short)r;
}

// ---------------------------------------------------------------------------
// K0: W1 [H][AD] f32 -> W1T bf16 [AD][H], per stream. Coalesced reads.
// ---------------------------------------------------------------------------
__global__ __launch_bounds__(256) void k_convert_w1(
    const float* __restrict__ w1_pre, const float* __restrict__ w1_fol,
    unsigned short* __restrict__ w1t) {
  int idx = blockIdx.x * 256 + threadIdx.x;  // 0..65535
  int st = blockIdx.y;
  const float* w1 = st ? w1_fol : w1_pre;
  int k = idx >> 7;       // 0..511
  int d = idx & 127;      // 0..127
  w1t[(size_t)st * AD_ * H_ + (size_t)d * H_ + k] = f2bf(w1[(size_t)k * AD_ + d]);
}

// ---------------------------------------------------------------------------
// K1: logits[st][m][r] = tanh(x_m @ W1) @ W2   (m = n*256+s, x row = emb[s][n][:])
// 64-row M-tile, full AD=128, K=512 in 16 steps of 32. bf16 MFMA 16x16x32.
// ---------------------------------------------------------------------------
__global__ __launch_bounds__(256) void k_logits(
    const float* __restrict__ emb_pre, const float* __restrict__ emb_fol,
    const unsigned short* __restrict__ w1t_all,
    const float* __restrict__ w2_pre, const float* __restrict__ w2_fol,
    float* __restrict__ logits) {
  const int st = blockIdx.y;
  const float* __restrict__ emb = st ? emb_fol : emb_pre;
  const float* __restrict__ w2  = st ? w2_fol : w2_pre;
  const unsigned short* __restrict__ w1t = w1t_all + (size_t)st * AD_ * H_;

  const int m0 = blockIdx.x * 64;
  const int n  = m0 >> 8;     // 64 | 256 so all rows of a tile share n
  const int s0 = m0 & 255;

  __shared__ __align__(16) unsigned short As[64][40];   // +8 pad: 16B-aligned, kills conflicts
  __shared__ __align__(16) unsigned short Bs[128][40];

  const int tid  = threadIdx.x;
  const int wave = tid >> 6;
  const int lane = tid & 63;

  f32x4 acc[8];
#pragma unroll
  for (int c = 0; c < 8; ++c) acc[c] = (f32x4){0.f, 0.f, 0.f, 0.f};

  // A staging: 64 rows x 32 k; 4 threads/row, 8 f32 each
  const int arow = tid >> 2;
  const int ak   = (tid & 3) * 8;
  const float* asrc_base = emb + ((size_t)(s0 + arow) * N_ + n) * H_ + ak;
  // B staging: 128 rows (d) x 32 k; 2 threads/row, 16 bf16 each
  const int bd = tid >> 1;
  const int bk = (tid & 1) * 16;
  const unsigned short* bsrc_base = w1t + (size_t)bd * H_ + bk;

  for (int kk = 0; kk < 16; ++kk) {
    {  // stage A (f32 -> bf16)
      const float4* src = (const float4*)(asrc_base + kk * 32);
      float4 v0 = src[0];
      float4 v1 = src[1];
      uint4 p;
      p.x = (unsigned)f2bf(v0.x) | ((unsigned)f2bf(v0.y) << 16);
      p.y = (unsigned)f2bf(v0.z) | ((unsigned)f2bf(v0.w) << 16);
      p.z = (unsigned)f2bf(v1.x) | ((unsigned)f2bf(v1.y) << 16);
      p.w = (unsigned)f2bf(v1.z) | ((unsigned)f2bf(v1.w) << 16);
      *(uint4*)&As[arow][ak] = p;
    }
    {  // stage B (already bf16, transposed)
      const uint4* src = (const uint4*)(bsrc_base + (size_t)kk * 32);
      uint4 b0 = src[0];
      uint4 b1 = src[1];
      *(uint4*)&Bs[bd][bk] = b0;
      *(uint4*)&Bs[bd][bk + 8] = b1;
    }
    __syncthreads();
    const int rowA = wave * 16 + (lane & 15);
    const int kofs = (lane >> 4) * 8;
    short8 a = *(const short8*)&As[rowA][kofs];
#pragma unroll
    for (int c = 0; c < 8; ++c) {
      short8 b = *(const short8*)&Bs[c * 16 + (lane & 15)][kofs];
      acc[c] = __builtin_amdgcn_mfma_f32_16x16x32_bf16(a, b, acc[c], 0, 0, 0);
    }
    __syncthreads();
  }

  // epilogue: tanh then @W2 (AD=128 -> 2), reduce across the 16 col-lanes
  float th[8][4];
#pragma unroll
  for (int c = 0; c < 8; ++c)
#pragma unroll
    for (int q = 0; q < 4; ++q) th[c][q] = tanhf(acc[c][q]);

  const int colb = lane & 15;
  float w2v[8][2];
#pragma unroll
  for (int c = 0; c < 8; ++c) {
    int d = c * 16 + colb;
    w2v[c][0] = w2[d * 2 + 0];
    w2v[c][1] = w2[d * 2 + 1];
  }
  float pr[4][2];
#pragma unroll
  for (int q = 0; q < 4; ++q)
#pragma unroll
    for (int r = 0; r < 2; ++r) {
      float p = 0.f;
#pragma unroll
      for (int c = 0; c < 8; ++c) p += th[c][q] * w2v[c][r];
      p += __shfl_xor(p, 1);
      p += __shfl_xor(p, 2);
      p += __shfl_xor(p, 4);
      p += __shfl_xor(p, 8);
      pr[q][r] = p;
    }
  if ((lane & 15) == 0) {
    int rbase = m0 + wave * 16 + (lane >> 4) * 4;
#pragma unroll
    for (int q = 0; q < 4; ++q)
#pragma unroll
      for (int r = 0; r < 2; ++r)
        logits[((size_t)st * M_TOTAL + rbase + q) * 2 + r] = pr[q][r];
  }
}

// ---------------------------------------------------------------------------
// K2: per (stream, n): double softmax over S with mask, fold mean over r.
// ---------------------------------------------------------------------------
template <bool MAXRED>
__device__ __forceinline__ float blockRed(float v, float* buf) {
#pragma unroll
  for (int off = 32; off; off >>= 1) {
    float o = __shfl_xor(v, off);
    v = MAXRED ? fmaxf(v, o) : (v + o);
  }
  int w = threadIdx.x >> 6;
  __syncthreads();
  if ((threadIdx.x & 63) == 0) buf[w] = v;
  __syncthreads();
  float r = buf[0];
#pragma unroll
  for (int i = 1; i < 4; ++i) r = MAXRED ? fmaxf(r, buf[i]) : (r + buf[i]);
  return r;
}

__global__ __launch_bounds__(256) void k_softmax(
    const float* __restrict__ logits,
    const unsigned char* __restrict__ mask_pre, const unsigned char* __restrict__ mask_fol,
    float* __restrict__ wbar) {
  const int n  = blockIdx.x;
  const int st = blockIdx.y;
  const unsigned char* mask = st ? mask_fol : mask_pre;
  const int s = threadIdx.x;

  float2 l = *(const float2*)&logits[((size_t)st * M_TOTAL + (size_t)n * S_ + s) * 2];
  const bool mk = mask[(size_t)n * S_ + s] != 0;

  __shared__ float buf[4];
  float q[2];
  float lv[2] = {l.x, l.y};
#pragma unroll
  for (int r = 0; r < 2; ++r) {
    float m1 = blockRed<true>(lv[r], buf);
    float e1 = __expf(lv[r] - m1);
    float s1 = blockRed<false>(e1, buf);
    float p1 = e1 / s1;                       // first softmax (unmasked)
    float v  = mk ? -INFINITY : p1;           // mask the probabilities
    float m2 = blockRed<true>(v, buf);
    float e2 = mk ? 0.f : __expf(v - m2);
    float s2 = blockRed<false>(e2, buf);
    q[r] = e2 / s2;                           // second softmax
  }
  wbar[((size_t)st * N_ + n) * S_ + s] = 0.5f * (q[0] + q[1]);
}

// ---------------------------------------------------------------------------
// K2b: inclusive prefix sum of is_valid -> pos (rank-1), per stream.
// ---------------------------------------------------------------------------
__global__ __launch_bounds__(1024) void k_scan(
    const int* __restrict__ valid_pre, const int* __restrict__ valid_fol,
    int* __restrict__ pos) {
  const int st = blockIdx.x;
  const int* valid = st ? valid_fol : valid_pre;
  __shared__ int buf[1024];
  const int t = threadIdx.x;
  buf[t] = valid[t];
  __syncthreads();
  for (int off = 1; off < 1024; off <<= 1) {
    int v = (t >= off) ? buf[t - off] : 0;
    __syncthreads();
    buf[t] += v;
    __syncthreads();
  }
  pos[st * N_ + t] = buf[t] - 1;
}

// ---------------------------------------------------------------------------
// K3: out[n][st*512 + h] = valid[n] ? sum_s wbar[pos[n]][s] * emb[s][pos[n]][h] : 0
// ---------------------------------------------------------------------------
__global__ __launch_bounds__(256) void k_pv(
    const float* __restrict__ emb_pre, const float* __restrict__ emb_fol,
    const float* __restrict__ wbar, const int* __restrict__ pos,
    const int* __restrict__ valid_pre, const int* __restrict__ valid_fol,
    float* __restrict__ out) {
  const int n  = blockIdx.x;
  const int st = blockIdx.y;
  const float* __restrict__ emb = st ? emb_fol : emb_pre;
  const int* valid = st ? valid_fol : valid_pre;
  float* __restrict__ o = out + (size_t)n * 1024 + st * 512;
  const int t = threadIdx.x;

  if (valid[n] <= 0) {
    o[2 * t] = 0.f;
    o[2 * t + 1] = 0.f;
    return;
  }
  const int np = pos[st * N_ + n];

  __shared__ float wl[S_];
  __shared__ __align__(16) float part[2][128][4];
  wl[t < S_ ? t : 0] = wbar[((size_t)st * N_ + np) * S_ + (t < S_ ? t : 0)];
  __syncthreads();

  const int g  = t >> 7;          // 0: even s, 1: odd s
  const int h4 = (t & 127) * 4;
  float4 acc = {0.f, 0.f, 0.f, 0.f};
  for (int s = g; s < S_; s += 2) {
    const float4 x = *(const float4*)(emb + ((size_t)s * N_ + np) * H_ + h4);
    const float w = wl[s];
    acc.x += w * x.x;
    acc.y += w * x.y;
    acc.z += w * x.z;
    acc.w += w * x.w;
  }
  *(float4*)&part[g][t & 127][0] = acc;
  __syncthreads();
  if (t < 128) {
    float4 a = *(const float4*)&part[0][t][0];
    float4 b = *(const float4*)&part[1][t][0];
    float4 r = {a.x + b.x, a.y + b.y, a.z + b.z, a.w + b.w};
    *(float4*)&o[t * 4] = r;
  }
}

// ---------------------------------------------------------------------------
extern "C" void kernel_launch(void* const* d_in, const int* in_sizes, int n_in,
                              void* d_out, int out_size, void* d_ws, size_t ws_size,
                              hipStream_t stream) {
  const float* emb_pre = (const float*)d_in[0];
  const float* emb_fol = (const float*)d_in[1];
  const unsigned char* mask_pre = (const unsigned char*)d_in[2];
  const unsigned char* mask_fol = (const unsigned char*)d_in[3];
  const int* valid_pre = (const int*)d_in[4];
  const int* valid_fol = (const int*)d_in[5];
  const float* w1_pre = (const float*)d_in[6];
  const float* w2_pre = (const float*)d_in[7];
  const float* w1_fol = (const float*)d_in[8];
  const float* w2_fol = (const float*)d_in[9];
  float* out = (float*)d_out;

  char* ws = (char*)d_ws;
  unsigned short* w1t = (unsigned short*)ws;                       // 256 KiB
  float* logits = (float*)(ws + 262144);                           // 4 MiB
  float* wbar   = (float*)(ws + 262144 + 4194304);                 // 2 MiB
  int*   pos    = (int*)(ws + 262144 + 4194304 + 2097152);         // 8 KiB

  hipLaunchKernelGGL(k_convert_w1, dim3(256, 2), dim3(256), 0, stream,
                     w1_pre, w1_fol, w1t);
  hipLaunchKernelGGL(k_logits, dim3(M_TOTAL / 64, 2), dim3(256), 0, stream,
                     emb_pre, emb_fol, w1t, w2_pre, w2_fol, logits);
  hipLaunchKernelGGL(k_softmax, dim3(N_, 2), dim3(256), 0, stream,
                     logits, mask_pre, mask_fol, wbar);
  hipLaunchKernelGGL(k_scan, dim3(2), dim3(1024), 0, stream,
                     valid_pre, valid_fol, pos);
  hipLaunchKernelGGL(k_pv, dim3(N_, 2), dim3(256), 0, stream,
                     emb_pre, emb_fol, wbar, pos, valid_pre, valid_fol, out);
}